// Round 6
// baseline (139.802 us; speedup 1.0000x reference)
//
#include <hip/hip_runtime.h>
#include <cstddef>

#define ZDIM 64
#define PDIM 4096          // Z*Z
#define PB   256           // p's per block (= blockDim)
#define BCHUNK 16          // batch rows per block (8 row-pairs, fully unrolled)
#define NPAIR (BCHUNK/2)

typedef float v2f __attribute__((ext_vector_type(2)));

__device__ __forceinline__ v2f pkfma(v2f a, v2f b, v2f c) {
    return __builtin_elementwise_fma(a, b, c);
}
__device__ __forceinline__ v2f splat(float s) { v2f r; r.x = s; r.y = s; return r; }

// Odd Pade(7,6) tanh split into numerator/denominator (validated R3/R5:
// absmax identical to exp-based reference rounds). |x| <= ~5.2 ok.
struct ND { v2f n, d; };
__device__ __forceinline__ ND tanh_nd(v2f x) {
    v2f t = x * x;
    v2f np = t + splat(378.0f);
    np = pkfma(np, t, splat(17325.0f));
    np = pkfma(np, t, splat(135135.0f));
    v2f dp = pkfma(splat(28.0f), t, splat(3150.0f));
    dp = pkfma(dp, t, splat(62370.0f));
    dp = pkfma(dp, t, splat(135135.0f));
    ND r; r.n = x * np; r.d = dp;
    return r;
}

// Montgomery batch inversion of 4 v2f denominators: 1 rcp per lane-half
// (2 scalar rcp) instead of 8. Exact reassociation, no overflow
// (max product ~1.5e26 < 3.4e38).
__device__ __forceinline__ void batch_inv4(v2f d0, v2f d1, v2f d2, v2f d3,
                                           v2f& i0, v2f& i1, v2f& i2, v2f& i3) {
    v2f P1 = d0 * d1;
    v2f P2 = P1 * d2;
    v2f P3 = P2 * d3;
    v2f R;
    R.x = __builtin_amdgcn_rcpf(P3.x);
    R.y = __builtin_amdgcn_rcpf(P3.y);
    i3 = R * P2;  R = R * d3;
    i2 = R * P1;  R = R * d2;
    i1 = R * d0;  i0 = R * d1;
}

__global__ void __launch_bounds__(PB) pair_mlp_kernel(
    const float* __restrict__ x,
    const float* __restrict__ W1, const float* __restrict__ b1,
    const float* __restrict__ g1, const float* __restrict__ be1,
    const float* __restrict__ W2, const float* __restrict__ b2,
    const float* __restrict__ g2, const float* __restrict__ be2,
    const float* __restrict__ W3, const float* __restrict__ b3,
    float* __restrict__ out, int nbc)
{
    const int tid = threadIdx.x;
    const int pb  = blockIdx.x / nbc;          // p-tile (0..15)
    const int bc  = blockIdx.x - pb * nbc;     // batch chunk
    const int p   = pb * PB + tid;
    const int z   = __builtin_amdgcn_readfirstlane(p >> 6);  // wave-uniform
    const int zp  = p & 63;
    const int b0  = bc * BCHUNK;

    // -------- preload x for the whole chunk (no loads inside compute) --------
    const float* xrow = x + (size_t)b0 * ZDIM;
    float cvr[BCHUNK], avr[BCHUNK];
    #pragma unroll
    for (int r = 0; r < BCHUNK; ++r) {
        cvr[r] = xrow[r * ZDIM + zp];   // per-lane, coalesced
        avr[r] = xrow[r * ZDIM + z];    // wave-uniform -> s_load
    }

    // ---------------- load per-p weights ----------------
    const float4* W1v = reinterpret_cast<const float4*>(W1 + (size_t)p * 8);
    const float4 w1x = W1v[0];
    const float4 w1y = W1v[1];
    const float4 b1v  = reinterpret_cast<const float4*>(b1)[p];
    const float4 g1v  = reinterpret_cast<const float4*>(g1)[p];
    const float4 be1v = reinterpret_cast<const float4*>(be1)[p];
    float w2[4][4];
    {
        const float4* W2v = reinterpret_cast<const float4*>(W2 + (size_t)p * 16);
        #pragma unroll
        for (int i = 0; i < 4; ++i) {
            float4 r = W2v[i];
            w2[i][0] = r.x; w2[i][1] = r.y; w2[i][2] = r.z; w2[i][3] = r.w;
        }
    }
    const float4 b2v  = reinterpret_cast<const float4*>(b2)[p];
    const float4 g2v  = reinterpret_cast<const float4*>(g2)[p];
    const float4 be2v = reinterpret_cast<const float4*>(be2)[p];
    const float4 w3v  = reinterpret_cast<const float4*>(W3)[p];
    const float  b3s  = b3[p];

    const float w1a[4] = {w1x.x, w1x.y, w1x.z, w1x.w};
    const float w1b[4] = {w1y.x, w1y.y, w1y.z, w1y.w};
    const float b1a[4] = {b1v.x, b1v.y, b1v.z, b1v.w};
    const float g1a[4] = {g1v.x, g1v.y, g1v.z, g1v.w};
    const float be1a[4]= {be1v.x, be1v.y, be1v.z, be1v.w};
    const float b2a[4] = {b2v.x, b2v.y, b2v.z, b2v.w};
    const float g2a[4] = {g2v.x, g2v.y, g2v.z, g2v.w};
    const float be2a[4]= {be2v.x, be2v.y, be2v.z, be2v.w};
    const float w3a[4] = {w3v.x, w3v.y, w3v.z, w3v.w};

    // ---- fold LN1 affine into layer 2, LN2 affine into layer 3 (centered) ----
    float w2g[4][4], b2p[4];
    #pragma unroll
    for (int j = 0; j < 4; ++j) b2p[j] = b2a[j];
    #pragma unroll
    for (int i = 0; i < 4; ++i) {
        #pragma unroll
        for (int j = 0; j < 4; ++j) {
            w2g[i][j] = g1a[i] * w2[i][j];
            b2p[j] = __builtin_fmaf(be1a[i], w2[i][j], b2p[j]);
        }
    }
    // sigmoid(y) = 0.5 + 0.5*tanh(y/2): fold the 1/2 into layer-3 weights
    float w3h[4], b3h = b3s;
    #pragma unroll
    for (int j = 0; j < 4; ++j) {
        b3h = __builtin_fmaf(be2a[j], w3a[j], b3h);
        w3h[j] = 0.5f * g2a[j] * w3a[j];
    }
    b3h *= 0.5f;

    float* obase = out + (size_t)b0 * PDIM + p;

    // ---------------- fully unrolled: 8 row-pairs, zero loads ----------------
    #pragma unroll
    for (int k = 0; k < NPAIR; ++k) {
        v2f a2, c2;
        a2.x = avr[2 * k]; a2.y = avr[2 * k + 1];
        c2.x = cvr[2 * k]; c2.y = cvr[2 * k + 1];

        // layer 1 + tanh (batched inversion)
        ND q0 = tanh_nd(pkfma(a2, splat(w1a[0]), pkfma(c2, splat(w1b[0]), splat(b1a[0]))));
        ND q1 = tanh_nd(pkfma(a2, splat(w1a[1]), pkfma(c2, splat(w1b[1]), splat(b1a[1]))));
        ND q2 = tanh_nd(pkfma(a2, splat(w1a[2]), pkfma(c2, splat(w1b[2]), splat(b1a[2]))));
        ND q3 = tanh_nd(pkfma(a2, splat(w1a[3]), pkfma(c2, splat(w1b[3]), splat(b1a[3]))));
        v2f i0, i1, i2, i3;
        batch_inv4(q0.d, q1.d, q2.d, q3.d, i0, i1, i2, i3);
        v2f t0 = q0.n * i0, t1 = q1.n * i1, t2 = q2.n * i2, t3 = q3.n * i3;

        // LN1 moments
        v2f s1 = (t0 + t1) + (t2 + t3);
        v2f s2 = pkfma(t0, t0, pkfma(t1, t1, pkfma(t2, t2, t3 * t3)));
        v2f m  = s1 * 0.25f;
        v2f t1e = pkfma(s2, splat(0.25f), splat(1e-5f));
        v2f var = pkfma(s1 * splat(-0.0625f), s1, t1e);
        v2f rs; rs.x = __builtin_amdgcn_rsqf(var.x); rs.y = __builtin_amdgcn_rsqf(var.y);
        v2f d0 = t0 - m, d1 = t1 - m, d2 = t2 - m, d3 = t3 - m;

        // layer 2 (LN1 folded) + tanh (batched inversion)
        v2f acc;
        acc = pkfma(d0, splat(w2g[0][0]), pkfma(d1, splat(w2g[1][0]), pkfma(d2, splat(w2g[2][0]), d3 * splat(w2g[3][0]))));
        ND r0 = tanh_nd(pkfma(rs, acc, splat(b2p[0])));
        acc = pkfma(d0, splat(w2g[0][1]), pkfma(d1, splat(w2g[1][1]), pkfma(d2, splat(w2g[2][1]), d3 * splat(w2g[3][1]))));
        ND r1 = tanh_nd(pkfma(rs, acc, splat(b2p[1])));
        acc = pkfma(d0, splat(w2g[0][2]), pkfma(d1, splat(w2g[1][2]), pkfma(d2, splat(w2g[2][2]), d3 * splat(w2g[3][2]))));
        ND r2 = tanh_nd(pkfma(rs, acc, splat(b2p[2])));
        acc = pkfma(d0, splat(w2g[0][3]), pkfma(d1, splat(w2g[1][3]), pkfma(d2, splat(w2g[2][3]), d3 * splat(w2g[3][3]))));
        ND r3 = tanh_nd(pkfma(rs, acc, splat(b2p[3])));
        v2f j0, j1, j2, j3;
        batch_inv4(r0.d, r1.d, r2.d, r3.d, j0, j1, j2, j3);
        v2f u0 = r0.n * j0, u1 = r1.n * j1, u2 = r2.n * j2, u3 = r3.n * j3;

        // LN2 moments
        v2f q1m = (u0 + u1) + (u2 + u3);
        v2f q2m = pkfma(u0, u0, pkfma(u1, u1, pkfma(u2, u2, u3 * u3)));
        v2f m2  = q1m * 0.25f;
        v2f t2e = pkfma(q2m, splat(0.25f), splat(1e-5f));
        v2f var2 = pkfma(q1m * splat(-0.0625f), q1m, t2e);
        v2f rs2; rs2.x = __builtin_amdgcn_rsqf(var2.x); rs2.y = __builtin_amdgcn_rsqf(var2.y);
        v2f e0 = u0 - m2, e1 = u1 - m2, e2 = u2 - m2, e3 = u3 - m2;

        // layer 3 (LN2 + 0.5 folded) + sigmoid via tanh
        v2f acc3 = pkfma(e0, splat(w3h[0]), pkfma(e1, splat(w3h[1]), pkfma(e2, splat(w3h[2]), e3 * splat(w3h[3]))));
        v2f sarg = pkfma(rs2, acc3, splat(b3h));   // = y/2
        ND qs = tanh_nd(sarg);
        // batch-2 inversion of the two lane-halves
        float Pd = qs.d.x * qs.d.y;
        float Rr = __builtin_amdgcn_rcpf(Pd);
        v2f inv; inv.x = Rr * qs.d.y; inv.y = Rr * qs.d.x;
        v2f th = qs.n * inv;
        v2f res = pkfma(th, splat(0.5f), splat(0.5f));

        obase[(size_t)(2 * k) * PDIM]     = res.x;
        obase[(size_t)(2 * k + 1) * PDIM] = res.y;
    }
}

extern "C" void kernel_launch(void* const* d_in, const int* in_sizes, int n_in,
                              void* d_out, int out_size, void* d_ws, size_t ws_size,
                              hipStream_t stream) {
    const float* x   = (const float*)d_in[0];
    const float* W1  = (const float*)d_in[1];
    const float* b1  = (const float*)d_in[2];
    const float* g1  = (const float*)d_in[3];
    const float* be1 = (const float*)d_in[4];
    const float* W2  = (const float*)d_in[5];
    const float* b2  = (const float*)d_in[6];
    const float* g2  = (const float*)d_in[7];
    const float* be2 = (const float*)d_in[8];
    const float* W3  = (const float*)d_in[9];
    const float* b3  = (const float*)d_in[10];
    float* out = (float*)d_out;

    const int B   = in_sizes[0] / ZDIM;     // 4096
    const int nbc = B / BCHUNK;             // 256
    const int grid = (PDIM / PB) * nbc;     // 16 * 256 = 4096

    hipLaunchKernelGGL(pair_mlp_kernel, dim3(grid), dim3(PB), 0, stream,
                       x, W1, b1, g1, be1, W2, b2, g2, be2, W3, b3, out, nbc);
}

// Round 7
// 130.654 us; speedup vs baseline: 1.0700x; 1.0700x over previous
//
#include <hip/hip_runtime.h>
#include <cstddef>

#define ZDIM 64
#define PDIM 4096          // Z*Z
#define PB   256           // p's per block (= blockDim)
#define BCHUNK 16          // batch rows per block (8 row-pairs, fully unrolled)
#define NPAIR (BCHUNK/2)

typedef float v2f __attribute__((ext_vector_type(2)));

__device__ __forceinline__ v2f pkfma(v2f a, v2f b, v2f c) {
    return __builtin_elementwise_fma(a, b, c);
}
__device__ __forceinline__ v2f splat(float s) { v2f r; r.x = s; r.y = s; return r; }

// Odd Pade(5,4) tanh: x(945+105t+t^2)/(945+420t+15t^2), t=x^2.
// err < 1e-4 for |x|<2.5 (typical range here), ~3e-3 at |x|=4.3 (abs worst case),
// damped by LN error-cancellation downstream. 7 pk + 2 rcp.
__device__ __forceinline__ v2f tanh54(v2f x) {
    v2f t = x * x;
    v2f num = x * pkfma(t, t + splat(105.0f), splat(945.0f));
    v2f den = pkfma(pkfma(splat(15.0f), t, splat(420.0f)), t, splat(945.0f));
    v2f r; r.x = __builtin_amdgcn_rcpf(den.x); r.y = __builtin_amdgcn_rcpf(den.y);
    return num * r;
}

__global__ void __launch_bounds__(PB) pair_mlp_kernel(
    const float* __restrict__ x,
    const float* __restrict__ W1, const float* __restrict__ b1,
    const float* __restrict__ g1, const float* __restrict__ be1,
    const float* __restrict__ W2, const float* __restrict__ b2,
    const float* __restrict__ g2, const float* __restrict__ be2,
    const float* __restrict__ W3, const float* __restrict__ b3,
    float* __restrict__ out, int nbc)
{
    const int tid = threadIdx.x;
    const int pb  = blockIdx.x / nbc;          // p-tile (0..15)
    const int bc  = blockIdx.x - pb * nbc;     // batch chunk
    const int p   = pb * PB + tid;
    const int z   = __builtin_amdgcn_readfirstlane(p >> 6);  // wave-uniform
    const int zp  = p & 63;
    const int b0  = bc * BCHUNK;

    // -------- stage x chunk (16 rows x 64) into LDS: frees 16 VGPRs --------
    __shared__ float xs[BCHUNK * ZDIM];   // 4 KB
    {
        const float4* xg = reinterpret_cast<const float4*>(x + (size_t)b0 * ZDIM);
        reinterpret_cast<float4*>(xs)[tid] = xg[tid];   // 1024 floats, coalesced
    }

    // -------- a-side: wave-uniform x values -> SGPRs via s_load --------
    const float* xrow = x + (size_t)b0 * ZDIM;
    float avr[BCHUNK];
    #pragma unroll
    for (int r = 0; r < BCHUNK; ++r)
        avr[r] = xrow[r * ZDIM + z];

    // ---------------- load per-p weights ----------------
    const float4* W1v = reinterpret_cast<const float4*>(W1 + (size_t)p * 8);
    const float4 w1x = W1v[0];
    const float4 w1y = W1v[1];
    const float4 b1v  = reinterpret_cast<const float4*>(b1)[p];
    const float4 g1v  = reinterpret_cast<const float4*>(g1)[p];
    const float4 be1v = reinterpret_cast<const float4*>(be1)[p];
    float w2[4][4];
    {
        const float4* W2v = reinterpret_cast<const float4*>(W2 + (size_t)p * 16);
        #pragma unroll
        for (int i = 0; i < 4; ++i) {
            float4 r = W2v[i];
            w2[i][0] = r.x; w2[i][1] = r.y; w2[i][2] = r.z; w2[i][3] = r.w;
        }
    }
    const float4 b2v  = reinterpret_cast<const float4*>(b2)[p];
    const float4 g2v  = reinterpret_cast<const float4*>(g2)[p];
    const float4 be2v = reinterpret_cast<const float4*>(be2)[p];
    const float4 w3v  = reinterpret_cast<const float4*>(W3)[p];
    const float  b3s  = b3[p];

    const float w1a[4] = {w1x.x, w1x.y, w1x.z, w1x.w};
    const float w1b[4] = {w1y.x, w1y.y, w1y.z, w1y.w};
    const float b1a[4] = {b1v.x, b1v.y, b1v.z, b1v.w};
    const float g1a[4] = {g1v.x, g1v.y, g1v.z, g1v.w};
    const float be1a[4]= {be1v.x, be1v.y, be1v.z, be1v.w};
    const float b2a[4] = {b2v.x, b2v.y, b2v.z, b2v.w};
    const float g2a[4] = {g2v.x, g2v.y, g2v.z, g2v.w};
    const float be2a[4]= {be2v.x, be2v.y, be2v.z, be2v.w};
    const float w3a[4] = {w3v.x, w3v.y, w3v.z, w3v.w};

    // ---- fold LN1 affine into layer 2, LN2 affine into layer 3 (centered) ----
    float w2g[4][4], b2p[4];
    #pragma unroll
    for (int j = 0; j < 4; ++j) b2p[j] = b2a[j];
    #pragma unroll
    for (int i = 0; i < 4; ++i) {
        #pragma unroll
        for (int j = 0; j < 4; ++j) {
            w2g[i][j] = g1a[i] * w2[i][j];
            b2p[j] = __builtin_fmaf(be1a[i], w2[i][j], b2p[j]);
        }
    }
    float w3g[4], b3p = b3s;
    #pragma unroll
    for (int j = 0; j < 4; ++j) {
        w3g[j] = g2a[j] * w3a[j];
        b3p = __builtin_fmaf(be2a[j], w3a[j], b3p);
    }

    float* obase = out + (size_t)b0 * PDIM + p;

    __syncthreads();   // xs ready

    // ---------------- fully unrolled: 8 row-pairs ----------------
    #pragma unroll
    for (int k = 0; k < NPAIR; ++k) {
        v2f a2, c2;
        a2.x = avr[2 * k]; a2.y = avr[2 * k + 1];
        c2.x = xs[(2 * k) * ZDIM + zp];       // DS pipe, constant offsets
        c2.y = xs[(2 * k + 1) * ZDIM + zp];

        // layer 1 + tanh
        v2f t0 = tanh54(pkfma(a2, splat(w1a[0]), pkfma(c2, splat(w1b[0]), splat(b1a[0]))));
        v2f t1 = tanh54(pkfma(a2, splat(w1a[1]), pkfma(c2, splat(w1b[1]), splat(b1a[1]))));
        v2f t2 = tanh54(pkfma(a2, splat(w1a[2]), pkfma(c2, splat(w1b[2]), splat(b1a[2]))));
        v2f t3 = tanh54(pkfma(a2, splat(w1a[3]), pkfma(c2, splat(w1b[3]), splat(b1a[3]))));

        // LN1: mean, centered variance
        v2f s1 = (t0 + t1) + (t2 + t3);
        v2f m  = s1 * 0.25f;
        v2f d0 = t0 - m, d1 = t1 - m, d2 = t2 - m, d3 = t3 - m;
        v2f sd = pkfma(d0, d0, pkfma(d1, d1, pkfma(d2, d2, d3 * d3)));
        v2f var = pkfma(sd, splat(0.25f), splat(1e-5f));
        v2f rs; rs.x = __builtin_amdgcn_rsqf(var.x); rs.y = __builtin_amdgcn_rsqf(var.y);

        // layer 2 (LN1 folded) + tanh
        v2f acc;
        acc = pkfma(d0, splat(w2g[0][0]), pkfma(d1, splat(w2g[1][0]), pkfma(d2, splat(w2g[2][0]), d3 * splat(w2g[3][0]))));
        v2f u0 = tanh54(pkfma(rs, acc, splat(b2p[0])));
        acc = pkfma(d0, splat(w2g[0][1]), pkfma(d1, splat(w2g[1][1]), pkfma(d2, splat(w2g[2][1]), d3 * splat(w2g[3][1]))));
        v2f u1 = tanh54(pkfma(rs, acc, splat(b2p[1])));
        acc = pkfma(d0, splat(w2g[0][2]), pkfma(d1, splat(w2g[1][2]), pkfma(d2, splat(w2g[2][2]), d3 * splat(w2g[3][2]))));
        v2f u2 = tanh54(pkfma(rs, acc, splat(b2p[2])));
        acc = pkfma(d0, splat(w2g[0][3]), pkfma(d1, splat(w2g[1][3]), pkfma(d2, splat(w2g[2][3]), d3 * splat(w2g[3][3]))));
        v2f u3 = tanh54(pkfma(rs, acc, splat(b2p[3])));

        // LN2: mean, centered variance
        v2f q1 = (u0 + u1) + (u2 + u3);
        v2f m2 = q1 * 0.25f;
        v2f e0 = u0 - m2, e1 = u1 - m2, e2 = u2 - m2, e3 = u3 - m2;
        v2f se = pkfma(e0, e0, pkfma(e1, e1, pkfma(e2, e2, e3 * e3)));
        v2f var2 = pkfma(se, splat(0.25f), splat(1e-5f));
        v2f rs2; rs2.x = __builtin_amdgcn_rsqf(var2.x); rs2.y = __builtin_amdgcn_rsqf(var2.y);

        // layer 3 (LN2 folded) + sigmoid (exp form)
        v2f acc3 = pkfma(e0, splat(w3g[0]), pkfma(e1, splat(w3g[1]), pkfma(e2, splat(w3g[2]), e3 * splat(w3g[3]))));
        v2f sarg = pkfma(rs2, acc3, splat(b3p));
        v2f q = sarg * splat(-1.4426950408889634f);
        v2f e; e.x = __builtin_amdgcn_exp2f(q.x); e.y = __builtin_amdgcn_exp2f(q.y);
        v2f ep1 = e + splat(1.0f);

        obase[(size_t)(2 * k) * PDIM]     = __builtin_amdgcn_rcpf(ep1.x);
        obase[(size_t)(2 * k + 1) * PDIM] = __builtin_amdgcn_rcpf(ep1.y);
    }
}

extern "C" void kernel_launch(void* const* d_in, const int* in_sizes, int n_in,
                              void* d_out, int out_size, void* d_ws, size_t ws_size,
                              hipStream_t stream) {
    const float* x   = (const float*)d_in[0];
    const float* W1  = (const float*)d_in[1];
    const float* b1  = (const float*)d_in[2];
    const float* g1  = (const float*)d_in[3];
    const float* be1 = (const float*)d_in[4];
    const float* W2  = (const float*)d_in[5];
    const float* b2  = (const float*)d_in[6];
    const float* g2  = (const float*)d_in[7];
    const float* be2 = (const float*)d_in[8];
    const float* W3  = (const float*)d_in[9];
    const float* b3  = (const float*)d_in[10];
    float* out = (float*)d_out;

    const int B   = in_sizes[0] / ZDIM;     // 4096
    const int nbc = B / BCHUNK;             // 256
    const int grid = (PDIM / PB) * nbc;     // 16 * 256 = 4096

    hipLaunchKernelGGL(pair_mlp_kernel, dim3(grid), dim3(PB), 0, stream,
                       x, W1, b1, g1, be1, W2, b2, g2, be2, W3, b3, out, nbc);
}